// Round 1
// 164.770 us; speedup vs baseline: 1.0006x; 1.0006x over previous
//
#include <hip/hip_runtime.h>

// Pose_Loss: B=65536 rows, D=154 cols, 4 fp32 arrays + 2 int mask arrays.
// out[0] = (dot(use_l, rowsum(recon_l)) + dot(use_r, rowsum(recon_r))) / 154
// out[1] =  dot(use_l, rowsum(KLD_l))   + dot(use_r, rowsum(KLD_r))
// out[2] =  sum(use_l) + sum(use_r)   (integer count, stored as float)
//
// R7 = grid-stride persistent blocks.
// Evidence (R6 rocprof): all top-5 dispatches are harness fillBuffer
// restores (256 MiB each @ 6.2-6.5 TB/s = HBM achievable ceiling); our
// kernels are each <41 us. Controllable slice of the 164.9 us window is
// ~30-45 us vs a 25.6 us read floor (161.5 MB @ 6.3 TB/s).
// Changes vs R6:
//  - BLOCKS 9856 -> 2048 (exactly 8 blocks/CU, 32 waves/CU occupancy);
//    each thread accumulates ~4.8 float4 chunks before one reduction
//    (4.8x fewer shfl/LDS/partial ops per byte loaded).
//  - ws partials 9856 -> 2048 entries (118 KB -> 24 KB round trip);
//    final_reduce touches 24 KB instead of 118 KB.
//  - Deterministic two-stage reduction kept (no atomic reordering risk).
//  - nt (non-temporal) loads kept: streamed data must not evict the
//    hot mask arrays or allocate L3 lines we'll never reuse.
//  - D = 154 = 2*77 => a float2 half never straddles a row. float4 chunk i
//    covers halves 2i, 2i+1 with rows (2i)/77, (2i+1)/77 (branch-free).

#define BB 65536
#define DD 154
#define N4 (BB * DD / 4)            // 2,523,136 float4 chunks
#define BLOCKS 2048
#define THREADS 256
#define STRIDE (BLOCKS * THREADS)   // 524,288 threads

typedef float nt_float4 __attribute__((ext_vector_type(4)));

__global__ void zero_out_kernel(float* __restrict__ out) {
    if (threadIdx.x < 3) out[threadIdx.x] = 0.0f;
}

__device__ __forceinline__ float2 wpair(int l, int f) {
    const bool valid = (f != -1);
    float2 w;
    w.x = (valid && ((l == 0) || (l == 2))) ? 1.0f : 0.0f;
    w.y = (valid && ((l == 1) || (l == 2))) ? 1.0f : 0.0f;
    return w;
}

// ws layout: ws[0..BLOCKS) = recon partials, [B..2B) = kld, [2B..3B) = cnt
__global__ __launch_bounds__(THREADS) void pose_partial_kernel(
    const float* __restrict__ recon_l, const float* __restrict__ recon_r,
    const float* __restrict__ kld_l,   const float* __restrict__ kld_r,
    const int* __restrict__ lr,        const int* __restrict__ fp,
    float* __restrict__ ws,            float* __restrict__ out)
{
    const nt_float4* __restrict__ rl4 = (const nt_float4*)recon_l;
    const nt_float4* __restrict__ rr4 = (const nt_float4*)recon_r;
    const nt_float4* __restrict__ kl4 = (const nt_float4*)kld_l;
    const nt_float4* __restrict__ kr4 = (const nt_float4*)kld_r;

    const int gid = blockIdx.x * THREADS + threadIdx.x;

    float acc_recon = 0.0f, acc_kld = 0.0f;

    // Grid-stride over float4 chunks: consecutive threads hit consecutive
    // 16B chunks each iteration -> fully coalesced 1 KiB/wave transactions.
    for (int i = gid; i < N4; i += STRIDE) {
        const int h  = 2 * i;
        const int r0 = h / 77;          // row of elements 4i, 4i+1
        const int r1 = (h + 1) / 77;    // row of elements 4i+2, 4i+3

        // non-temporal streaming loads: read once, do not allocate
        const nt_float4 a = __builtin_nontemporal_load(&rl4[i]);
        const nt_float4 b = __builtin_nontemporal_load(&rr4[i]);
        const nt_float4 c = __builtin_nontemporal_load(&kl4[i]);
        const nt_float4 d = __builtin_nontemporal_load(&kr4[i]);

        // weight lookups stay cached (512 KB total, heavily reused)
        const float2 w0 = wpair(lr[r0], fp[r0]);
        const float2 w1 = wpair(lr[r1], fp[r1]);

        acc_recon += w0.x * (a.x + a.y) + w1.x * (a.z + a.w)
                   + w0.y * (b.x + b.y) + w1.y * (b.z + b.w);
        acc_kld   += w0.x * (c.x + c.y) + w1.x * (c.z + c.w)
                   + w0.y * (d.x + d.y) + w1.y * (d.z + d.w);
    }

    // Count: one row per thread, first BB threads (coalesced mask reads).
    float acc_cnt = 0.0f;
    if (gid < BB) {
        const float2 w = wpair(lr[gid], fp[gid]);
        acc_cnt = w.x + w.y;
    }

#pragma unroll
    for (int off = 32; off > 0; off >>= 1) {
        acc_recon += __shfl_down(acc_recon, off, 64);
        acc_kld   += __shfl_down(acc_kld,   off, 64);
        acc_cnt   += __shfl_down(acc_cnt,   off, 64);
    }

    __shared__ float s_recon[4], s_kld[4], s_cnt[4];
    const int wave = threadIdx.x >> 6;
    const int lane = threadIdx.x & 63;
    if (lane == 0) {
        s_recon[wave] = acc_recon;
        s_kld[wave]   = acc_kld;
        s_cnt[wave]   = acc_cnt;
    }
    __syncthreads();

    if (threadIdx.x == 0) {
        const float r = s_recon[0] + s_recon[1] + s_recon[2] + s_recon[3];
        const float k = s_kld[0]   + s_kld[1]   + s_kld[2]   + s_kld[3];
        const float n = s_cnt[0]   + s_cnt[1]   + s_cnt[2]   + s_cnt[3];
        if (ws != nullptr) {
            ws[blockIdx.x]              = r;
            ws[BLOCKS + blockIdx.x]     = k;
            ws[2 * BLOCKS + blockIdx.x] = n;
        } else {
            atomicAdd(&out[0], r * (1.0f / 154.0f));
            atomicAdd(&out[1], k);
            atomicAdd(&out[2], n);
        }
    }
}

__global__ __launch_bounds__(1024) void final_reduce_kernel(
    const float* __restrict__ ws, float* __restrict__ out)
{
    float r = 0.0f, k = 0.0f, n = 0.0f;
    for (int i = threadIdx.x; i < BLOCKS; i += 1024) {
        r += ws[i];
        k += ws[BLOCKS + i];
        n += ws[2 * BLOCKS + i];
    }
#pragma unroll
    for (int off = 32; off > 0; off >>= 1) {
        r += __shfl_down(r, off, 64);
        k += __shfl_down(k, off, 64);
        n += __shfl_down(n, off, 64);
    }
    __shared__ float s_r[16], s_k[16], s_n[16];
    const int wave = threadIdx.x >> 6;
    const int lane = threadIdx.x & 63;
    if (lane == 0) { s_r[wave] = r; s_k[wave] = k; s_n[wave] = n; }
    __syncthreads();
    if (threadIdx.x == 0) {
        float rr = 0.0f, kk = 0.0f, nn = 0.0f;
#pragma unroll
        for (int w = 0; w < 16; ++w) { rr += s_r[w]; kk += s_k[w]; nn += s_n[w]; }
        out[0] = rr * (1.0f / 154.0f);
        out[1] = kk;
        out[2] = nn;
    }
}

extern "C" void kernel_launch(void* const* d_in, const int* in_sizes, int n_in,
                              void* d_out, int out_size, void* d_ws, size_t ws_size,
                              hipStream_t stream) {
    const float* recon_l = (const float*)d_in[0];
    const float* recon_r = (const float*)d_in[1];
    const float* kld_l   = (const float*)d_in[2];
    const float* kld_r   = (const float*)d_in[3];
    const int*   lr      = (const int*)d_in[4];
    const int*   fp      = (const int*)d_in[5];
    float* out = (float*)d_out;

    const bool use_ws = (d_ws != nullptr) &&
                        (ws_size >= (size_t)(3 * BLOCKS) * sizeof(float));
    float* ws = use_ws ? (float*)d_ws : nullptr;

    if (!use_ws) {
        zero_out_kernel<<<1, 64, 0, stream>>>(out);
    }
    pose_partial_kernel<<<BLOCKS, THREADS, 0, stream>>>(
        recon_l, recon_r, kld_l, kld_r, lr, fp, ws, out);
    if (use_ws) {
        final_reduce_kernel<<<1, 1024, 0, stream>>>(ws, out);
    }
}